// Round 12
// baseline (457.761 us; speedup 1.0000x reference)
//
#include <hip/hip_runtime.h>

typedef unsigned short u16;
typedef __attribute__((ext_vector_type(8))) short bf16x8;   // 8 bf16 = 4 VGPRs
typedef __attribute__((ext_vector_type(4))) float f32x4;

#define EMBED 1024
#define FFDIM 4096
#define SEQ   2048
#define NTOK  8192
#define ATT_C 0.18033688011112042f   // 0.125 * log2(e)

__device__ __forceinline__ u16 f2bf(float f) {              // RNE fp32->bf16
  union { float f; unsigned int u; } c; c.f = f;
  unsigned int r = ((c.u >> 16) & 1u) + 0x7fffu;
  return (u16)((c.u + r) >> 16);
}

__device__ __forceinline__ unsigned cvtpk(float lo, float hi) {
  unsigned r;
  asm("v_cvt_pk_bf16_f32 %0, %1, %2" : "=v"(r) : "v"(lo), "v"(hi));
  return r;
}

__device__ __forceinline__ void gload16(const u16* g, u16* l) {
  __builtin_amdgcn_global_load_lds((const __attribute__((address_space(1))) void*)g,
                                   (__attribute__((address_space(3))) void*)l, 16, 0, 0);
}

// ---------------- fp32 [K][N] -> bf16 [N][K] (B^T layout for GEMM) -----------
__global__ __launch_bounds__(256) void wtrans(const float* __restrict__ W,
                                              u16* __restrict__ Wt, int K, int N) {
  __shared__ float tile[32][33];
  const int tx = threadIdx.x & 31, ty = threadIdx.x >> 5;
  const int n0 = blockIdx.x << 5, k0 = blockIdx.y << 5;
#pragma unroll
  for (int r = 0; r < 32; r += 8)
    tile[ty + r][tx] = W[(size_t)(k0 + ty + r) * N + n0 + tx];
  __syncthreads();
#pragma unroll
  for (int r = 0; r < 32; r += 8)
    Wt[(size_t)(n0 + ty + r) * K + k0 + tx] = f2bf(tile[tx][ty + r]);
}

// ---------------- V part of qkv [token][2048+h*64+d] -> Vt [bh*64+d][t] ------
__global__ __launch_bounds__(256) void vtrans(const u16* __restrict__ qkv,
                                              u16* __restrict__ Vt) {
  __shared__ u16 tile[32][33];
  const int tx = threadIdx.x & 31, ty = threadIdx.x >> 5;
  const int t0 = blockIdx.x << 5;
  const int rg0 = blockIdx.y << 5;            // global V row = bh*64 + d
  const int bh = rg0 >> 6, d0 = rg0 & 63;
  const int b = bh >> 4, h = bh & 15;
#pragma unroll
  for (int r = 0; r < 32; r += 8)
    tile[ty + r][tx] = qkv[(size_t)(b * SEQ + t0 + ty + r) * 3072 + 2048 + h * 64 + d0 + tx];
  __syncthreads();
#pragma unroll
  for (int r = 0; r < 32; r += 8)
    Vt[(size_t)(rg0 + ty + r) * SEQ + t0 + tx] = tile[tx][ty + r];
}

// ---------------- LayerNorm fp32 in -> bf16 out ------------------------------
__global__ __launch_bounds__(256) void ln_kernel(const float* __restrict__ xin,
                                                 const float* __restrict__ gamma,
                                                 const float* __restrict__ beta,
                                                 u16* __restrict__ out) {
  const int row = blockIdx.x, tid = threadIdx.x;
  const float4 v = reinterpret_cast<const float4*>(xin + (size_t)row * EMBED)[tid];
  float s  = v.x + v.y + v.z + v.w;
  float ss = v.x * v.x + v.y * v.y + v.z * v.z + v.w * v.w;
#pragma unroll
  for (int m = 1; m < 64; m <<= 1) { s += __shfl_xor(s, m); ss += __shfl_xor(ss, m); }
  __shared__ float red[8];
  if ((tid & 63) == 0) { red[tid >> 6] = s; red[4 + (tid >> 6)] = ss; }
  __syncthreads();
  s  = red[0] + red[1] + red[2] + red[3];
  ss = red[4] + red[5] + red[6] + red[7];
  const float mean = s * (1.0f / EMBED);
  const float var  = ss * (1.0f / EMBED) - mean * mean;
  const float rstd = rsqrtf(var + 1e-5f);
  const float4 g  = reinterpret_cast<const float4*>(gamma)[tid];
  const float4 bb = reinterpret_cast<const float4*>(beta)[tid];
  ushort4 o;
  o.x = f2bf((v.x - mean) * rstd * g.x + bb.x);
  o.y = f2bf((v.y - mean) * rstd * g.y + bb.y);
  o.z = f2bf((v.z - mean) * rstd * g.z + bb.z);
  o.w = f2bf((v.w - mean) * rstd * g.w + bb.w);
  reinterpret_cast<ushort4*>(out + (size_t)row * EMBED)[tid] = o;
}

// ---------------- bf16 GEMM v4: block-quadrant 8-phase counted pipeline -------
// 256xBN tile, 8 waves. Phase q computes BLOCK C-quadrant (mh,nh) in order
// (0,0),(0,1),(1,1),(1,0): each phase needs ONE A-half + ONE B-half; af/bf
// register sets are reused across phases (low pressure). Stages (1 half/phase,
// into buf cn) lead their first use by 3-4 phases; per-wave counted vmcnt
// gates (never drain mid-loop):
//   ph0: rdA0+rdB0 | stA0' | bar lgkm0 | MFMA q0 | vm(G0) bar
//   ph1: rdB1      | stB0' | bar lgkm0 | MFMA q1 | vm(G1) bar
//   ph2: rdA1      | stB1' | bar lgkm0 | MFMA q2 |        bar
//   ph3: rdB0      | stA1' | bar lgkm0 | MFMA q3 | vm(G3) bar
// EPI 0: bf16 | 1: +bias +res -> fp32 | 2: +bias GELU -> bf16
template <int NREP, int EPI>
__global__ __launch_bounds__(512, 2) void gemm4(const u16* __restrict__ A,
                                                const u16* __restrict__ Bt,
                                                void* __restrict__ Cv,
                                                const float* __restrict__ bias,
                                                const float* __restrict__ res,
                                                int M, int N, int K) {
  constexpr int BN = NREP * 64;
  constexpr int G0 = 4;
  constexpr int G1 = (NREP == 4) ? 4 : 3;
  constexpr int G3 = (NREP == 4) ? 4 : 3;
  constexpr int GP = (NREP == 4) ? 4 : 3;
  __shared__ __align__(16) u16 As[2][256 * 64];    // [row][k] swizzled
  __shared__ __align__(16) u16 Bs[2][BN * 64];     // [col][k] swizzled

  const int tid = threadIdx.x;
  const int lane = tid & 63, wid = tid >> 6;
  const int l4 = lane >> 4, l15 = lane & 15;
  const int wq = wid >> 2, wn = wid & 3;           // wave sub-pos in quadrant

  const int gx = gridDim.x;
  const int nwg = gx * (int)gridDim.y;
  const int flat = (int)blockIdx.y * gx + (int)blockIdx.x;
  const int cpx = nwg >> 3;                        // bijective XCD swizzle
  const int swz = (flat & 7) * cpx + (flat >> 3);
  const int brow = (swz / gx) << 8;
  const int bcol = (swz % gx) * BN;

  const f32x4 z4 = {0.f, 0.f, 0.f, 0.f};
  f32x4 acc[4][4][NREP / 2];                       // [quadrant][m][n2]
#pragma unroll
  for (int q = 0; q < 4; ++q)
#pragma unroll
    for (int m = 0; m < 4; ++m)
#pragma unroll
      for (int n = 0; n < NREP / 2; ++n) acc[q][m][n] = z4;

  // staging: linear LDS dest, pre-XOR'd global source column (involution)
  const int srow = tid >> 3;                       // 0..63
  const int scolb = ((tid & 7) << 4) ^ ((srow & 7) << 4);
  const u16* gAs = A  + (size_t)(brow + srow) * K + (scolb >> 1);
  const u16* gBs = Bt + (size_t)(bcol + srow) * K + (scolb >> 1);
  const int lA = wid * 512;                        // wave-uniform LDS u16 base

  const int nk = K >> 6;

#define STAGE_A(c_, t_, h_)                                                     \
  do {                                                                          \
    gload16(gAs + (size_t)((h_) * 128) * K + (size_t)(t_) * 64,                 \
            &As[c_][(h_) * 8192 + lA]);                                         \
    gload16(gAs + (size_t)((h_) * 128 + 64) * K + (size_t)(t_) * 64,            \
            &As[c_][(h_) * 8192 + 4096 + lA]);                                  \
  } while (0)
#define STAGE_B(c_, t_, h_)                                                     \
  do {                                                                          \
    if constexpr (NREP == 4) {                                                  \
      gload16(gBs + (size_t)((h_) * 128) * K + (size_t)(t_) * 64,               \
              &Bs[c_][(h_) * 8192 + lA]);                                       \
      gload16(gBs + (size_t)((h_) * 128 + 64) * K + (size_t)(t_) * 64,          \
              &Bs[c_][(h_) * 8192 + 4096 + lA]);                                \
    } else {                                                                    \
      gload16(gBs + (size_t)((h_) * 64) * K + (size_t)(t_) * 64,                \
              &Bs[c_][(h_) * 4096 + lA]);                                       \
    }                                                                           \
  } while (0)

#define SB __builtin_amdgcn_sched_barrier(0)
#define BARR do { SB; __builtin_amdgcn_s_barrier(); SB; } while (0)
#define LG0  do { asm volatile("s_waitcnt lgkmcnt(0)" ::: "memory"); SB; } while (0)
#define VM(N_) do { asm volatile("s_waitcnt vmcnt(%0)" :: "i"(N_) : "memory"); SB; } while (0)

  const int kk0  = l4 << 3;
  const int aswz = (l15 & 7) << 3;

#define RD_A(MH)                                                                \
  _Pragma("unroll")                                                             \
  for (int m_ = 0; m_ < 4; ++m_)                                                \
    _Pragma("unroll")                                                           \
    for (int ks_ = 0; ks_ < 2; ++ks_)                                           \
      af[m_][ks_] = *(const bf16x8*)&As[c][((MH) * 128 + wq * 64 + m_ * 16 + l15) * 64 + ((kk0 + ks_ * 32) ^ aswz)];
#define RD_B(NH)                                                                \
  _Pragma("unroll")                                                             \
  for (int n_ = 0; n_ < NREP / 2; ++n_)                                         \
    _Pragma("unroll")                                                           \
    for (int ks_ = 0; ks_ < 2; ++ks_)                                           \
      bf[n_][ks_] = *(const bf16x8*)&Bs[c][((NH) * (BN / 2) + wn * (BN / 8) + n_ * 16 + l15) * 64 + ((kk0 + ks_ * 32) ^ aswz)];
#define MFMA_Q(Q_)                                                              \
  __builtin_amdgcn_s_setprio(1);                                                \
  _Pragma("unroll")                                                             \
  for (int m_ = 0; m_ < 4; ++m_)                                                \
    _Pragma("unroll")                                                           \
    for (int n_ = 0; n_ < NREP / 2; ++n_)                                       \
      _Pragma("unroll")                                                         \
      for (int ks_ = 0; ks_ < 2; ++ks_)                                         \
        acc[Q_][m_][n_] = __builtin_amdgcn_mfma_f32_16x16x32_bf16(              \
            af[m_][ks_], bf[n_][ks_], acc[Q_][m_][n_], 0, 0, 0);                \
  __builtin_amdgcn_s_setprio(0);

  bf16x8 af[4][2], bf[NREP / 2][2];

  // prologue: tile 0's halves A0,B0,B1,A1 -> land A0,B0; B1,A1 stay in flight
  STAGE_A(0, 0, 0);
  STAGE_B(0, 0, 0);
  STAGE_B(0, 0, 1);
  STAGE_A(0, 0, 1);
  VM(GP);
  BARR;

  for (int t = 0; t < nk - 1; ++t) {
    const int c = t & 1, cn = c ^ 1;
    // ph0: quadrant (0,0)
    RD_A(0); RD_B(0);
    STAGE_A(cn, t + 1, 0);
    BARR; LG0;
    MFMA_Q(0);
    VM(G0); BARR;
    // ph1: quadrant (0,1)
    RD_B(1);
    STAGE_B(cn, t + 1, 0);
    BARR; LG0;
    MFMA_Q(1);
    VM(G1); BARR;
    // ph2: quadrant (1,1)
    RD_A(1);
    STAGE_B(cn, t + 1, 1);
    BARR; LG0;
    MFMA_Q(2);
    BARR;
    // ph3: quadrant (1,0)
    RD_B(0);
    STAGE_A(cn, t + 1, 1);
    BARR; LG0;
    MFMA_Q(3);
    VM(G3); BARR;
  }

  {  // peeled last tile (no stages; drain 2 -> 0)
    const int c = (nk - 1) & 1;
    RD_A(0); RD_B(0);
    BARR; LG0;
    MFMA_Q(0);
    VM(2); BARR;
    RD_B(1);
    BARR; LG0;
    MFMA_Q(1);
    VM(0); BARR;
    RD_A(1);
    BARR; LG0;
    MFMA_Q(2);
    BARR;
    RD_B(0);
    LG0;
    MFMA_Q(3);
  }

#undef STAGE_A
#undef STAGE_B
#undef SB
#undef BARR
#undef LG0
#undef VM
#undef RD_A
#undef RD_B
#undef MFMA_Q

  // epilogue: C/D layout col = lane&15, row = (lane>>4)*4 + reg
#pragma unroll
  for (int q = 0; q < 4; ++q) {
    const int mh = q >> 1, nh = (q >> 1) ^ (q & 1);
    const int rowb = brow + mh * 128 + wq * 64 + (l4 << 2);
    const int colb = bcol + nh * (BN / 2) + wn * (BN / 8) + l15;
#pragma unroll
    for (int n = 0; n < NREP / 2; ++n) {
      const int col = colb + n * 16;
      float bv = 0.f;
      if (EPI != 0) bv = bias[col];
#pragma unroll
      for (int m = 0; m < 4; ++m) {
#pragma unroll
        for (int j = 0; j < 4; ++j) {
          const int row = rowb + m * 16 + j;
          const float v = acc[q][m][n][j];
          if (EPI == 0) {
            ((u16*)Cv)[(size_t)row * N + col] = f2bf(v);
          } else if (EPI == 1) {
            ((float*)Cv)[(size_t)row * N + col] = v + bv + res[(size_t)row * N + col];
          } else {
            const float t2 = v + bv;
            const float gl = 0.5f * t2 * (1.0f + erff(t2 * 0.70710678118654752f));
            ((u16*)Cv)[(size_t)row * N + col] = f2bf(gl);
          }
        }
      }
    }
  }
}

// ---------------- causal flash attention v5b (unchanged) ---------------------
__global__ __launch_bounds__(512) void attn_fwd(const u16* __restrict__ qkv,
                                                const u16* __restrict__ Vt,
                                                u16* __restrict__ attn) {
  __shared__ __align__(16) u16 Ks[64 * 72];
  __shared__ __align__(16) u16 Vs[64 * 72];
  __shared__ __align__(16) u16 Ps[8 * 16 * 72];
  const int tid = threadIdx.x, lane = tid & 63, wid = tid >> 6;
  const int l4 = lane >> 4, l15 = lane & 15;
  const int bh = blockIdx.y, b = bh >> 4, h = bh & 15;
  const size_t bt0 = (size_t)b * SEQ;
  u16* Pw = &Ps[wid * 16 * 72];

  const int sr = tid >> 3;
  const int sc0 = (tid & 7) << 3;
  const u16* kbase = qkv + bt0 * 3072 + 1024 + h * 64;
  const u16* vbase = Vt + (size_t)bh * 64 * SEQ;
  const f32x4 z4 = {0.f, 0.f, 0.f, 0.f};

#pragma unroll
  for (int ph = 0; ph < 2; ++ph) {
    const int Qb = ((ph == 0) ? (int)blockIdx.x : 15 - (int)blockIdx.x) << 7;
    const int qw = Qb + wid * 16;
    const int qlane = qw + l15;

    const u16* qp = qkv + (bt0 + qlane) * 3072 + h * 64 + (l4 << 3);
    const bf16x8 aq0 = *(const bf16x8*)qp;
    const bf16x8 aq1 = *(const bf16x8*)(qp + 32);

    f32x4 o[4];
#pragma unroll
    for (int dt = 0; dt < 4; ++dt) o[dt] = z4;
    float mrun = -1e30f, lrun = 0.f;

    bf16x8 kp = *(const bf16x8*)(kbase + (size_t)sr * 3072 + sc0);
    bf16x8 vp = *(const bf16x8*)(vbase + (size_t)sr * SEQ + sc0);

    const int jend = Qb + 128;
    for (int j0 = 0; j0 < jend; j0 += 64) {
      __syncthreads();
      *(bf16x8*)&Ks[sr * 72 + sc0] = kp;
      *(bf16x8*)&Vs[sr * 72 + sc0] = vp;
      __syncthreads();

      if (j0 + 64 < jend) {
        kp = *(const bf16x8*)(kbase + (size_t)(j0 + 64 + sr) * 3072 + sc0);
        vp = *(const bf16x8*)(vbase + (size_t)sr * SEQ + j0 + 64 + sc0);
      }

      if (j0 > qw + 15) continue;
      const int nt = min(4, ((qw + 15 - j0) >> 4) + 1);

      f32x4 s[4];
#pragma unroll
      for (int t = 0; t < 4; ++t) {
        if (t < nt) {
          const bf16x8 ak0 = *(const bf16x8*)&Ks[(t * 16 + l15) * 72 + (l4 << 3)];
          const bf16x8 ak1 = *(const bf16x8*)&Ks[(t * 16 + l15) * 72 + 32 + (l4 << 3)];
          f32x4 a = z4;
          a = __builtin_amdgcn_mfma_f32_16x16x32_bf16(ak0, aq0, a, 0, 0, 0);
          a = __builtin_amdgcn_mfma_f32_16x16x32_bf16(ak1, aq1, a, 0, 0, 0);
          s[t] = a;
        }
      }

      float mt = -1e30f;
#pragma unroll
      for (int t = 0; t < 4; ++t) {
        if (t < nt) {
          if (j0 + t * 16 + 15 > qw) {
            const int kvb = j0 + t * 16 + (l4 << 2);
#pragma unroll
            for (int j = 0; j < 4; ++j)
              if (kvb + j > qlane) s[t][j] = -1e30f;
          }
          mt = fmaxf(mt, fmaxf(fmaxf(s[t][0], s[t][1]), fmaxf(s[t][2], s[t][3])));
        }
      }
      mt = fmaxf(mt, __shfl_xor(mt, 16));
      mt = fmaxf(mt, __shfl_xor(mt, 32));

      const bool skip = __all(mt <= mrun + 44.0f);
      float scq = 1.0f;
      if (!skip) {
        const float mn = fmaxf(mrun, mt);
        scq = exp2f((mrun - mn) * ATT_C);
        mrun = mn;
      }
      const float mc = mrun * ATT_C;

      float ls = 0.f;
      uint2 pw[4];
#pragma unroll
      for (int t = 0; t < 4; ++t) {
        if (t < nt) {
          const float p0 = exp2f(__builtin_fmaf(s[t][0], ATT_C, -mc));
          const float p1 = exp2f(__builtin_fmaf(s[t][1], ATT_C, -mc));
          const float p2 = exp2f(__builtin_fmaf(s[t][2], ATT_C, -mc));
          const float p3 = exp2f(__builtin_fmaf(s[t][3], ATT_C, -mc));
          ls += (p0 + p1) + (p2 + p3);
          pw[t].x = cvtpk(p0, p1);
          pw[t].y = cvtpk(p2, p3);
        } else {
          pw[t].x = 0u; pw[t].y = 0u;
        }
      }
#pragma unroll
      for (int t = 0; t < 4; ++t)
        *(uint2*)&Pw[l15 * 72 + t * 16 + (l4 << 2)] = pw[t];

      ls += __shfl_xor(ls, 16);
      ls += __shfl_xor(ls, 32);

      if (!skip) {
        lrun = lrun * scq + ls;
#pragma unroll
        for (int dt = 0; dt < 4; ++dt)
#pragma unroll
          for (int j = 0; j < 4; ++j) o[dt][j] *= scq;
      } else {
        lrun += ls;
      }

      const int nc = (nt + 1) >> 1;
#pragma unroll
      for (int c = 0; c < 2; ++c) {
        if (c < nc) {
          const bf16x8 ap = *(const bf16x8*)&Pw[l15 * 72 + c * 32 + (l4 << 3)];
#pragma unroll
          for (int dt = 0; dt < 4; ++dt) {
            const bf16x8 bv = *(const bf16x8*)&Vs[(dt * 16 + l15) * 72 + c * 32 + (l4 << 3)];
            o[dt] = __builtin_amdgcn_mfma_f32_16x16x32_bf16(bv, ap, o[dt], 0, 0, 0);
          }
        }
      }
    }

    const float rl = 1.0f / lrun;
#pragma unroll
    for (int dt = 0; dt < 4; ++dt) {
      uint2 w;
      w.x = cvtpk(o[dt][0] * rl, o[dt][1] * rl);
      w.y = cvtpk(o[dt][2] * rl, o[dt][3] * rl);
      *(uint2*)&Pw[l15 * 72 + dt * 16 + (l4 << 2)] = w;
    }
#pragma unroll
    for (int rep = 0; rep < 2; ++rep) {
      const int unit = rep * 64 + lane;
      const int r = unit >> 3, c = unit & 7;
      const bf16x8 v = *(const bf16x8*)&Pw[r * 72 + c * 8];
      *(bf16x8*)&attn[(bt0 + qw + r) * EMBED + h * 64 + c * 8] = v;
    }
  }
}

// ---------------- driver ------------------------------------------------------
extern "C" void kernel_launch(void* const* d_in, const int* in_sizes, int n_in,
                              void* d_out, int out_size, void* d_ws, size_t ws_size,
                              hipStream_t stream) {
  const float* x   = (const float*)d_in[0];
  const float* Wq  = (const float*)d_in[1];
  const float* Wk  = (const float*)d_in[2];
  const float* Wv  = (const float*)d_in[3];
  const float* Wo  = (const float*)d_in[4];
  const float* bo  = (const float*)d_in[5];
  const float* W1  = (const float*)d_in[6];
  const float* b1  = (const float*)d_in[7];
  const float* W2  = (const float*)d_in[8];
  const float* b2  = (const float*)d_in[9];
  const float* g1  = (const float*)d_in[10];
  const float* be1 = (const float*)d_in[11];
  const float* g2  = (const float*)d_in[12];
  const float* be2 = (const float*)d_in[13];

  char* ws = (char*)d_ws;
  u16* wqkv_t = (u16*)(ws + 0);                 // [3072][1024] bf16   6 MB
  u16* wo_t   = (u16*)(ws + 6291456);           // [1024][1024]        2 MB
  u16* w1_t   = (u16*)(ws + 8388608);           // [4096][1024]        8 MB
  u16* w2_t   = (u16*)(ws + 16777216);          // [1024][4096]        8 MB
  u16* hbuf   = (u16*)(ws + 25165824);          // LN out, reused     16 MB
  u16* qkv    = (u16*)(ws + 41943040);          // [8192][3072]       48 MB
  u16* ff1    = (u16*)(ws + 41943040);          // overlaps qkv+Vt    64 MB
  u16* vt     = (u16*)(ws + 92274688);          // [64*64][2048]      16 MB
  u16* attnb  = (u16*)(ws + 109051904);         // [8192][1024]       16 MB
  float* x2   = (float*)(ws + 125829120);       // fp32 residual      32 MB
  float* outp = (float*)d_out;

  dim3 blk(256);
  wtrans<<<dim3(32, 32),  blk, 0, stream>>>(Wq, wqkv_t,               1024, 1024);
  wtrans<<<dim3(32, 32),  blk, 0, stream>>>(Wk, wqkv_t + 1024 * 1024, 1024, 1024);
  wtrans<<<dim3(32, 32),  blk, 0, stream>>>(Wv, wqkv_t + 2048 * 1024, 1024, 1024);
  wtrans<<<dim3(32, 32),  blk, 0, stream>>>(Wo, wo_t,                 1024, 1024);
  wtrans<<<dim3(128, 32), blk, 0, stream>>>(W1, w1_t,                 1024, 4096);
  wtrans<<<dim3(32, 128), blk, 0, stream>>>(W2, w2_t,                 4096, 1024);

  ln_kernel<<<dim3(8192), blk, 0, stream>>>(x, g1, be1, hbuf);
  gemm4<2, 0><<<dim3(24, 32), dim3(512), 0, stream>>>(hbuf, wqkv_t, qkv, nullptr, nullptr,
                                                      8192, 3072, 1024);
  vtrans<<<dim3(64, 128), blk, 0, stream>>>(qkv, vt);
  attn_fwd<<<dim3(8, 64), dim3(512), 0, stream>>>(qkv, vt, attnb);
  gemm4<2, 1><<<dim3(8, 32), dim3(512), 0, stream>>>(attnb, wo_t, x2, bo, x,
                                                     8192, 1024, 1024);
  ln_kernel<<<dim3(8192), blk, 0, stream>>>(x2, g2, be2, hbuf);
  gemm4<4, 2><<<dim3(16, 32), dim3(512), 0, stream>>>(hbuf, w1_t, ff1, b1, nullptr,
                                                      8192, 4096, 1024);
  gemm4<2, 1><<<dim3(8, 32), dim3(512), 0, stream>>>(ff1, w2_t, outp, b2, x2,
                                                     8192, 1024, 4096);
}

// Round 13
// 425.675 us; speedup vs baseline: 1.0754x; 1.0754x over previous
//
#include <hip/hip_runtime.h>

typedef unsigned short u16;
typedef __attribute__((ext_vector_type(8))) short bf16x8;   // 8 bf16 = 4 VGPRs
typedef __attribute__((ext_vector_type(4))) float f32x4;

#define EMBED 1024
#define FFDIM 4096
#define SEQ   2048
#define NTOK  8192
#define ATT_C 0.18033688011112042f   // 0.125 * log2(e)

__device__ __forceinline__ u16 f2bf(float f) {              // RNE fp32->bf16
  union { float f; unsigned int u; } c; c.f = f;
  unsigned int r = ((c.u >> 16) & 1u) + 0x7fffu;
  return (u16)((c.u + r) >> 16);
}

__device__ __forceinline__ unsigned cvtpk(float lo, float hi) {
  unsigned r;
  asm("v_cvt_pk_bf16_f32 %0, %1, %2" : "=v"(r) : "v"(lo), "v"(hi));
  return r;
}

__device__ __forceinline__ void gload16(const u16* g, u16* l) {
  __builtin_amdgcn_global_load_lds((const __attribute__((address_space(1))) void*)g,
                                   (__attribute__((address_space(3))) void*)l, 16, 0, 0);
}

// ---------------- fp32 [K][N] -> bf16 [N][K] (B^T layout for GEMM) -----------
__global__ __launch_bounds__(256) void wtrans(const float* __restrict__ W,
                                              u16* __restrict__ Wt, int K, int N) {
  __shared__ float tile[32][33];
  const int tx = threadIdx.x & 31, ty = threadIdx.x >> 5;
  const int n0 = blockIdx.x << 5, k0 = blockIdx.y << 5;
#pragma unroll
  for (int r = 0; r < 32; r += 8)
    tile[ty + r][tx] = W[(size_t)(k0 + ty + r) * N + n0 + tx];
  __syncthreads();
#pragma unroll
  for (int r = 0; r < 32; r += 8)
    Wt[(size_t)(n0 + ty + r) * K + k0 + tx] = f2bf(tile[tx][ty + r]);
}

// ---------------- V part of qkv [token][2048+h*64+d] -> Vt [bh*64+d][t] ------
__global__ __launch_bounds__(256) void vtrans(const u16* __restrict__ qkv,
                                              u16* __restrict__ Vt) {
  __shared__ u16 tile[32][33];
  const int tx = threadIdx.x & 31, ty = threadIdx.x >> 5;
  const int t0 = blockIdx.x << 5;
  const int rg0 = blockIdx.y << 5;            // global V row = bh*64 + d
  const int bh = rg0 >> 6, d0 = rg0 & 63;
  const int b = bh >> 4, h = bh & 15;
#pragma unroll
  for (int r = 0; r < 32; r += 8)
    tile[ty + r][tx] = qkv[(size_t)(b * SEQ + t0 + ty + r) * 3072 + 2048 + h * 64 + d0 + tx];
  __syncthreads();
#pragma unroll
  for (int r = 0; r < 32; r += 8)
    Vt[(size_t)(rg0 + ty + r) * SEQ + t0 + tx] = tile[tx][ty + r];
}

// ---------------- LayerNorm fp32 in -> bf16 out ------------------------------
__global__ __launch_bounds__(256) void ln_kernel(const float* __restrict__ xin,
                                                 const float* __restrict__ gamma,
                                                 const float* __restrict__ beta,
                                                 u16* __restrict__ out) {
  const int row = blockIdx.x, tid = threadIdx.x;
  const float4 v = reinterpret_cast<const float4*>(xin + (size_t)row * EMBED)[tid];
  float s  = v.x + v.y + v.z + v.w;
  float ss = v.x * v.x + v.y * v.y + v.z * v.z + v.w * v.w;
#pragma unroll
  for (int m = 1; m < 64; m <<= 1) { s += __shfl_xor(s, m); ss += __shfl_xor(ss, m); }
  __shared__ float red[8];
  if ((tid & 63) == 0) { red[tid >> 6] = s; red[4 + (tid >> 6)] = ss; }
  __syncthreads();
  s  = red[0] + red[1] + red[2] + red[3];
  ss = red[4] + red[5] + red[6] + red[7];
  const float mean = s * (1.0f / EMBED);
  const float var  = ss * (1.0f / EMBED) - mean * mean;
  const float rstd = rsqrtf(var + 1e-5f);
  const float4 g  = reinterpret_cast<const float4*>(gamma)[tid];
  const float4 bb = reinterpret_cast<const float4*>(beta)[tid];
  ushort4 o;
  o.x = f2bf((v.x - mean) * rstd * g.x + bb.x);
  o.y = f2bf((v.y - mean) * rstd * g.y + bb.y);
  o.z = f2bf((v.z - mean) * rstd * g.z + bb.z);
  o.w = f2bf((v.w - mean) * rstd * g.w + bb.w);
  reinterpret_cast<ushort4*>(out + (size_t)row * EMBED)[tid] = o;
}

// ---------------- bf16 GEMM v5: m201-faithful quadrant pipeline --------------
// Same geometry as gemm4 (256xBN, 8 waves, quadrants (0,0),(0,1),(1,1),(1,0)),
// but m201 scheduling discipline:
//  * per phase: reads | stage | s_barrier | lgkmcnt(0) | ONE sched_barrier |
//    setprio MFMA setprio | s_barrier          (no other pinning!)
//  * vmcnt ONCE per K-tile (end of ph4), counted: newest GP loads =
//    {A0(t+2), B1(t+2)}, so tile t+1 is fully landed, never drained.
//  * stage lead = 2 tiles: ph1 B0(t+1,cn), ph2 A1(t+1,cn) (cn idle all tile),
//    ph3 A0(t+2,c) (A0 slot freed after ph2 lgkm0), ph4 B1(t+2,c) (freed ph3).
// EPI 0: bf16 | 1: +bias +res -> fp32 | 2: +bias GELU -> bf16
template <int NREP, int EPI>
__global__ __launch_bounds__(512, 2) void gemm5(const u16* __restrict__ A,
                                                const u16* __restrict__ Bt,
                                                void* __restrict__ Cv,
                                                const float* __restrict__ bias,
                                                const float* __restrict__ res,
                                                int M, int N, int K) {
  constexpr int BN = NREP * 64;
  constexpr int GP = (NREP == 4) ? 4 : 3;          // gloads of 2 newest halves
  __shared__ __align__(16) u16 As[2][256 * 64];    // [row][k] swizzled
  __shared__ __align__(16) u16 Bs[2][BN * 64];     // [col][k] swizzled

  const int tid = threadIdx.x;
  const int lane = tid & 63, wid = tid >> 6;
  const int l4 = lane >> 4, l15 = lane & 15;
  const int wq = wid >> 2, wn = wid & 3;

  const int gx = gridDim.x;
  const int nwg = gx * (int)gridDim.y;
  const int flat = (int)blockIdx.y * gx + (int)blockIdx.x;
  const int cpx = nwg >> 3;                        // bijective XCD swizzle
  const int swz = (flat & 7) * cpx + (flat >> 3);
  const int brow = (swz / gx) << 8;
  const int bcol = (swz % gx) * BN;

  const f32x4 z4 = {0.f, 0.f, 0.f, 0.f};
  f32x4 acc[4][4][NREP / 2];                       // [quadrant][m][n2]
#pragma unroll
  for (int q = 0; q < 4; ++q)
#pragma unroll
    for (int m = 0; m < 4; ++m)
#pragma unroll
      for (int n = 0; n < NREP / 2; ++n) acc[q][m][n] = z4;

  const int srow = tid >> 3;                       // 0..63
  const int scolb = ((tid & 7) << 4) ^ ((srow & 7) << 4);
  const u16* gAs = A  + (size_t)(brow + srow) * K + (scolb >> 1);
  const u16* gBs = Bt + (size_t)(bcol + srow) * K + (scolb >> 1);
  const int lA = wid * 512;                        // wave-uniform LDS u16 base

  const int nk = K >> 6;

#define STAGE_A(c_, t_, h_)                                                     \
  do {                                                                          \
    gload16(gAs + (size_t)((h_) * 128) * K + (size_t)(t_) * 64,                 \
            &As[c_][(h_) * 8192 + lA]);                                         \
    gload16(gAs + (size_t)((h_) * 128 + 64) * K + (size_t)(t_) * 64,            \
            &As[c_][(h_) * 8192 + 4096 + lA]);                                  \
  } while (0)
#define STAGE_B(c_, t_, h_)                                                     \
  do {                                                                          \
    if constexpr (NREP == 4) {                                                  \
      gload16(gBs + (size_t)((h_) * 128) * K + (size_t)(t_) * 64,               \
              &Bs[c_][(h_) * 8192 + lA]);                                       \
      gload16(gBs + (size_t)((h_) * 128 + 64) * K + (size_t)(t_) * 64,          \
              &Bs[c_][(h_) * 8192 + 4096 + lA]);                                \
    } else {                                                                    \
      gload16(gBs + (size_t)((h_) * 64) * K + (size_t)(t_) * 64,                \
              &Bs[c_][(h_) * 4096 + lA]);                                       \
    }                                                                           \
  } while (0)

  const int kk0  = l4 << 3;
  const int aswz = (l15 & 7) << 3;

#define RD_A(MH)                                                                \
  _Pragma("unroll")                                                             \
  for (int m_ = 0; m_ < 4; ++m_)                                                \
    _Pragma("unroll")                                                           \
    for (int ks_ = 0; ks_ < 2; ++ks_)                                           \
      af[m_][ks_] = *(const bf16x8*)&As[c][((MH) * 128 + wq * 64 + m_ * 16 + l15) * 64 + ((kk0 + ks_ * 32) ^ aswz)];
#define RD_B(NH)                                                                \
  _Pragma("unroll")                                                             \
  for (int n_ = 0; n_ < NREP / 2; ++n_)                                         \
    _Pragma("unroll")                                                           \
    for (int ks_ = 0; ks_ < 2; ++ks_)                                           \
      bf[n_][ks_] = *(const bf16x8*)&Bs[c][((NH) * (BN / 2) + wn * (BN / 8) + n_ * 16 + l15) * 64 + ((kk0 + ks_ * 32) ^ aswz)];
#define GATE_LG                                                                 \
  __builtin_amdgcn_s_barrier();                                                 \
  asm volatile("s_waitcnt lgkmcnt(0)" ::: "memory");                            \
  __builtin_amdgcn_sched_barrier(0)
#define MFMA_Q(Q_)                                                              \
  __builtin_amdgcn_s_setprio(1);                                                \
  _Pragma("unroll")                                                             \
  for (int m_ = 0; m_ < 4; ++m_)                                                \
    _Pragma("unroll")                                                           \
    for (int n_ = 0; n_ < NREP / 2; ++n_)                                       \
      _Pragma("unroll")                                                         \
      for (int ks_ = 0; ks_ < 2; ++ks_)                                         \
        acc[Q_][m_][n_] = __builtin_amdgcn_mfma_f32_16x16x32_bf16(              \
            af[m_][ks_], bf[n_][ks_], acc[Q_][m_][n_], 0, 0, 0);                \
  __builtin_amdgcn_s_setprio(0);

  bf16x8 af[4][2], bf[NREP / 2][2];

  // prologue: tile0 fully + {A0,B1}(1); gate leaves exactly those GP in flight
  STAGE_A(0, 0, 0);
  STAGE_B(0, 0, 0);
  STAGE_B(0, 0, 1);
  STAGE_A(0, 0, 1);
  if (nk > 1) { STAGE_A(1, 1, 0); STAGE_B(1, 1, 1); }
  asm volatile("s_waitcnt vmcnt(%0)" :: "i"(GP) : "memory");
  __builtin_amdgcn_s_barrier();

  for (int t = 0; t < nk; ++t) {
    const int c = t & 1, cn = c ^ 1;
    // ph1: quadrant (0,0) -- reads A0,B0
    RD_A(0); RD_B(0);
    if (t + 1 < nk) STAGE_B(cn, t + 1, 0);
    if constexpr (NREP == 4) asm volatile("s_waitcnt lgkmcnt(8)" ::: "memory");
    GATE_LG;
    MFMA_Q(0);
    __builtin_amdgcn_s_barrier();
    // ph2: quadrant (0,1) -- reads B1 (A0 in regs)
    RD_B(1);
    if (t + 1 < nk) STAGE_A(cn, t + 1, 1);
    GATE_LG;
    MFMA_Q(1);
    __builtin_amdgcn_s_barrier();
    // ph3: quadrant (1,1) -- reads A1 (B1 in regs); A0 slot of buf c is free
    RD_A(1);
    if (t + 2 < nk) STAGE_A(c, t + 2, 0);
    GATE_LG;
    MFMA_Q(2);
    __builtin_amdgcn_s_barrier();
    // ph4: quadrant (1,0) -- re-reads B0 (A1 in regs); B1 slot of buf c free
    RD_B(0);
    if (t + 2 < nk) STAGE_B(c, t + 2, 1);
    GATE_LG;
    MFMA_Q(3);
    if (t + 2 < nk) {
      asm volatile("s_waitcnt vmcnt(%0)" :: "i"(GP) : "memory");
    } else {
      asm volatile("s_waitcnt vmcnt(0)" ::: "memory");
    }
    __builtin_amdgcn_s_barrier();
  }

#undef STAGE_A
#undef STAGE_B
#undef RD_A
#undef RD_B
#undef GATE_LG
#undef MFMA_Q

  // epilogue: C/D layout col = lane&15, row = (lane>>4)*4 + reg
#pragma unroll
  for (int q = 0; q < 4; ++q) {
    const int mh = q >> 1, nh = (q >> 1) ^ (q & 1);
    const int rowb = brow + mh * 128 + wq * 64 + (l4 << 2);
    const int colb = bcol + nh * (BN / 2) + wn * (BN / 8) + l15;
#pragma unroll
    for (int n = 0; n < NREP / 2; ++n) {
      const int col = colb + n * 16;
      float bv = 0.f;
      if (EPI != 0) bv = bias[col];
#pragma unroll
      for (int m = 0; m < 4; ++m) {
#pragma unroll
        for (int j = 0; j < 4; ++j) {
          const int row = rowb + m * 16 + j;
          const float v = acc[q][m][n][j];
          if (EPI == 0) {
            ((u16*)Cv)[(size_t)row * N + col] = f2bf(v);
          } else if (EPI == 1) {
            ((float*)Cv)[(size_t)row * N + col] = v + bv + res[(size_t)row * N + col];
          } else {
            const float t2 = v + bv;
            const float gl = 0.5f * t2 * (1.0f + erff(t2 * 0.70710678118654752f));
            ((u16*)Cv)[(size_t)row * N + col] = f2bf(gl);
          }
        }
      }
    }
  }
}

// ---------------- causal flash attention v5b (unchanged) ---------------------
__global__ __launch_bounds__(512) void attn_fwd(const u16* __restrict__ qkv,
                                                const u16* __restrict__ Vt,
                                                u16* __restrict__ attn) {
  __shared__ __align__(16) u16 Ks[64 * 72];
  __shared__ __align__(16) u16 Vs[64 * 72];
  __shared__ __align__(16) u16 Ps[8 * 16 * 72];
  const int tid = threadIdx.x, lane = tid & 63, wid = tid >> 6;
  const int l4 = lane >> 4, l15 = lane & 15;
  const int bh = blockIdx.y, b = bh >> 4, h = bh & 15;
  const size_t bt0 = (size_t)b * SEQ;
  u16* Pw = &Ps[wid * 16 * 72];

  const int sr = tid >> 3;
  const int sc0 = (tid & 7) << 3;
  const u16* kbase = qkv + bt0 * 3072 + 1024 + h * 64;
  const u16* vbase = Vt + (size_t)bh * 64 * SEQ;
  const f32x4 z4 = {0.f, 0.f, 0.f, 0.f};

#pragma unroll
  for (int ph = 0; ph < 2; ++ph) {
    const int Qb = ((ph == 0) ? (int)blockIdx.x : 15 - (int)blockIdx.x) << 7;
    const int qw = Qb + wid * 16;
    const int qlane = qw + l15;

    const u16* qp = qkv + (bt0 + qlane) * 3072 + h * 64 + (l4 << 3);
    const bf16x8 aq0 = *(const bf16x8*)qp;
    const bf16x8 aq1 = *(const bf16x8*)(qp + 32);

    f32x4 o[4];
#pragma unroll
    for (int dt = 0; dt < 4; ++dt) o[dt] = z4;
    float mrun = -1e30f, lrun = 0.f;

    bf16x8 kp = *(const bf16x8*)(kbase + (size_t)sr * 3072 + sc0);
    bf16x8 vp = *(const bf16x8*)(vbase + (size_t)sr * SEQ + sc0);

    const int jend = Qb + 128;
    for (int j0 = 0; j0 < jend; j0 += 64) {
      __syncthreads();
      *(bf16x8*)&Ks[sr * 72 + sc0] = kp;
      *(bf16x8*)&Vs[sr * 72 + sc0] = vp;
      __syncthreads();

      if (j0 + 64 < jend) {
        kp = *(const bf16x8*)(kbase + (size_t)(j0 + 64 + sr) * 3072 + sc0);
        vp = *(const bf16x8*)(vbase + (size_t)sr * SEQ + j0 + 64 + sc0);
      }

      if (j0 > qw + 15) continue;
      const int nt = min(4, ((qw + 15 - j0) >> 4) + 1);

      f32x4 s[4];
#pragma unroll
      for (int t = 0; t < 4; ++t) {
        if (t < nt) {
          const bf16x8 ak0 = *(const bf16x8*)&Ks[(t * 16 + l15) * 72 + (l4 << 3)];
          const bf16x8 ak1 = *(const bf16x8*)&Ks[(t * 16 + l15) * 72 + 32 + (l4 << 3)];
          f32x4 a = z4;
          a = __builtin_amdgcn_mfma_f32_16x16x32_bf16(ak0, aq0, a, 0, 0, 0);
          a = __builtin_amdgcn_mfma_f32_16x16x32_bf16(ak1, aq1, a, 0, 0, 0);
          s[t] = a;
        }
      }

      float mt = -1e30f;
#pragma unroll
      for (int t = 0; t < 4; ++t) {
        if (t < nt) {
          if (j0 + t * 16 + 15 > qw) {
            const int kvb = j0 + t * 16 + (l4 << 2);
#pragma unroll
            for (int j = 0; j < 4; ++j)
              if (kvb + j > qlane) s[t][j] = -1e30f;
          }
          mt = fmaxf(mt, fmaxf(fmaxf(s[t][0], s[t][1]), fmaxf(s[t][2], s[t][3])));
        }
      }
      mt = fmaxf(mt, __shfl_xor(mt, 16));
      mt = fmaxf(mt, __shfl_xor(mt, 32));

      const bool skip = __all(mt <= mrun + 44.0f);
      float scq = 1.0f;
      if (!skip) {
        const float mn = fmaxf(mrun, mt);
        scq = exp2f((mrun - mn) * ATT_C);
        mrun = mn;
      }
      const float mc = mrun * ATT_C;

      float ls = 0.f;
      uint2 pw[4];
#pragma unroll
      for (int t = 0; t < 4; ++t) {
        if (t < nt) {
          const float p0 = exp2f(__builtin_fmaf(s[t][0], ATT_C, -mc));
          const float p1 = exp2f(__builtin_fmaf(s[t][1], ATT_C, -mc));
          const float p2 = exp2f(__builtin_fmaf(s[t][2], ATT_C, -mc));
          const float p3 = exp2f(__builtin_fmaf(s[t][3], ATT_C, -mc));
          ls += (p0 + p1) + (p2 + p3);
          pw[t].x = cvtpk(p0, p1);
          pw[t].y = cvtpk(p2, p3);
        } else {
          pw[t].x = 0u; pw[t].y = 0u;
        }
      }
#pragma unroll
      for (int t = 0; t < 4; ++t)
        *(uint2*)&Pw[l15 * 72 + t * 16 + (l4 << 2)] = pw[t];

      ls += __shfl_xor(ls, 16);
      ls += __shfl_xor(ls, 32);

      if (!skip) {
        lrun = lrun * scq + ls;
#pragma unroll
        for (int dt = 0; dt < 4; ++dt)
#pragma unroll
          for (int j = 0; j < 4; ++j) o[dt][j] *= scq;
      } else {
        lrun += ls;
      }

      const int nc = (nt + 1) >> 1;
#pragma unroll
      for (int c = 0; c < 2; ++c) {
        if (c < nc) {
          const bf16x8 ap = *(const bf16x8*)&Pw[l15 * 72 + c * 32 + (l4 << 3)];
#pragma unroll
          for (int dt = 0; dt < 4; ++dt) {
            const bf16x8 bv = *(const bf16x8*)&Vs[(dt * 16 + l15) * 72 + c * 32 + (l4 << 3)];
            o[dt] = __builtin_amdgcn_mfma_f32_16x16x32_bf16(bv, ap, o[dt], 0, 0, 0);
          }
        }
      }
    }

    const float rl = 1.0f / lrun;
#pragma unroll
    for (int dt = 0; dt < 4; ++dt) {
      uint2 w;
      w.x = cvtpk(o[dt][0] * rl, o[dt][1] * rl);
      w.y = cvtpk(o[dt][2] * rl, o[dt][3] * rl);
      *(uint2*)&Pw[l15 * 72 + dt * 16 + (l4 << 2)] = w;
    }
#pragma unroll
    for (int rep = 0; rep < 2; ++rep) {
      const int unit = rep * 64 + lane;
      const int r = unit >> 3, c = unit & 7;
      const bf16x8 v = *(const bf16x8*)&Pw[r * 72 + c * 8];
      *(bf16x8*)&attn[(bt0 + qw + r) * EMBED + h * 64 + c * 8] = v;
    }
  }
}

// ---------------- driver ------------------------------------------------------
extern "C" void kernel_launch(void* const* d_in, const int* in_sizes, int n_in,
                              void* d_out, int out_size, void* d_ws, size_t ws_size,
                              hipStream_t stream) {
  const float* x   = (const float*)d_in[0];
  const float* Wq  = (const float*)d_in[1];
  const float* Wk  = (const float*)d_in[2];
  const float* Wv  = (const float*)d_in[3];
  const float* Wo  = (const float*)d_in[4];
  const float* bo  = (const float*)d_in[5];
  const float* W1  = (const float*)d_in[6];
  const float* b1  = (const float*)d_in[7];
  const float* W2  = (const float*)d_in[8];
  const float* b2  = (const float*)d_in[9];
  const float* g1  = (const float*)d_in[10];
  const float* be1 = (const float*)d_in[11];
  const float* g2  = (const float*)d_in[12];
  const float* be2 = (const float*)d_in[13];

  char* ws = (char*)d_ws;
  u16* wqkv_t = (u16*)(ws + 0);                 // [3072][1024] bf16   6 MB
  u16* wo_t   = (u16*)(ws + 6291456);           // [1024][1024]        2 MB
  u16* w1_t   = (u16*)(ws + 8388608);           // [4096][1024]        8 MB
  u16* w2_t   = (u16*)(ws + 16777216);          // [1024][4096]        8 MB
  u16* hbuf   = (u16*)(ws + 25165824);          // LN out, reused     16 MB
  u16* qkv    = (u16*)(ws + 41943040);          // [8192][3072]       48 MB
  u16* ff1    = (u16*)(ws + 41943040);          // overlaps qkv+Vt    64 MB
  u16* vt     = (u16*)(ws + 92274688);          // [64*64][2048]      16 MB
  u16* attnb  = (u16*)(ws + 109051904);         // [8192][1024]       16 MB
  float* x2   = (float*)(ws + 125829120);       // fp32 residual      32 MB
  float* outp = (float*)d_out;

  dim3 blk(256);
  wtrans<<<dim3(32, 32),  blk, 0, stream>>>(Wq, wqkv_t,               1024, 1024);
  wtrans<<<dim3(32, 32),  blk, 0, stream>>>(Wk, wqkv_t + 1024 * 1024, 1024, 1024);
  wtrans<<<dim3(32, 32),  blk, 0, stream>>>(Wv, wqkv_t + 2048 * 1024, 1024, 1024);
  wtrans<<<dim3(32, 32),  blk, 0, stream>>>(Wo, wo_t,                 1024, 1024);
  wtrans<<<dim3(128, 32), blk, 0, stream>>>(W1, w1_t,                 1024, 4096);
  wtrans<<<dim3(32, 128), blk, 0, stream>>>(W2, w2_t,                 4096, 1024);

  ln_kernel<<<dim3(8192), blk, 0, stream>>>(x, g1, be1, hbuf);
  gemm5<2, 0><<<dim3(24, 32), dim3(512), 0, stream>>>(hbuf, wqkv_t, qkv, nullptr, nullptr,
                                                      8192, 3072, 1024);
  vtrans<<<dim3(64, 128), blk, 0, stream>>>(qkv, vt);
  attn_fwd<<<dim3(8, 64), dim3(512), 0, stream>>>(qkv, vt, attnb);
  gemm5<2, 1><<<dim3(8, 32), dim3(512), 0, stream>>>(attnb, wo_t, x2, bo, x,
                                                     8192, 1024, 1024);
  ln_kernel<<<dim3(8192), blk, 0, stream>>>(x2, g2, be2, hbuf);
  gemm5<4, 2><<<dim3(16, 32), dim3(512), 0, stream>>>(hbuf, w1_t, ff1, b1, nullptr,
                                                      8192, 4096, 1024);
  gemm5<2, 1><<<dim3(8, 32), dim3(512), 0, stream>>>(ff1, w2_t, outp, b2, x2,
                                                     8192, 1024, 4096);
}

// Round 14
// 414.194 us; speedup vs baseline: 1.1052x; 1.0277x over previous
//
#include <hip/hip_runtime.h>

typedef unsigned short u16;
typedef __attribute__((ext_vector_type(8))) short bf16x8;   // 8 bf16 = 4 VGPRs
typedef __attribute__((ext_vector_type(4))) float f32x4;

#define EMBED 1024
#define FFDIM 4096
#define SEQ   2048
#define NTOK  8192
#define ATT_C 0.18033688011112042f   // 0.125 * log2(e)

__device__ __forceinline__ u16 f2bf(float f) {              // RNE fp32->bf16
  union { float f; unsigned int u; } c; c.f = f;
  unsigned int r = ((c.u >> 16) & 1u) + 0x7fffu;
  return (u16)((c.u + r) >> 16);
}

__device__ __forceinline__ unsigned cvtpk(float lo, float hi) {
  unsigned r;
  asm("v_cvt_pk_bf16_f32 %0, %1, %2" : "=v"(r) : "v"(lo), "v"(hi));
  return r;
}

__device__ __forceinline__ void gload16(const u16* g, u16* l) {
  __builtin_amdgcn_global_load_lds((const __attribute__((address_space(1))) void*)g,
                                   (__attribute__((address_space(3))) void*)l, 16, 0, 0);
}

// ---------------- fp32 [K][N] -> bf16 [N][K] (B^T layout for GEMM) -----------
__global__ __launch_bounds__(256) void wtrans(const float* __restrict__ W,
                                              u16* __restrict__ Wt, int K, int N) {
  __shared__ float tile[32][33];
  const int tx = threadIdx.x & 31, ty = threadIdx.x >> 5;
  const int n0 = blockIdx.x << 5, k0 = blockIdx.y << 5;
#pragma unroll
  for (int r = 0; r < 32; r += 8)
    tile[ty + r][tx] = W[(size_t)(k0 + ty + r) * N + n0 + tx];
  __syncthreads();
#pragma unroll
  for (int r = 0; r < 32; r += 8)
    Wt[(size_t)(n0 + ty + r) * K + k0 + tx] = f2bf(tile[tx][ty + r]);
}

// ---------------- V part of qkv [token][2048+h*64+d] -> Vt [bh*64+d][t] ------
__global__ __launch_bounds__(256) void vtrans(const u16* __restrict__ qkv,
                                              u16* __restrict__ Vt) {
  __shared__ u16 tile[32][33];
  const int tx = threadIdx.x & 31, ty = threadIdx.x >> 5;
  const int t0 = blockIdx.x << 5;
  const int rg0 = blockIdx.y << 5;            // global V row = bh*64 + d
  const int bh = rg0 >> 6, d0 = rg0 & 63;
  const int b = bh >> 4, h = bh & 15;
#pragma unroll
  for (int r = 0; r < 32; r += 8)
    tile[ty + r][tx] = qkv[(size_t)(b * SEQ + t0 + ty + r) * 3072 + 2048 + h * 64 + d0 + tx];
  __syncthreads();
#pragma unroll
  for (int r = 0; r < 32; r += 8)
    Vt[(size_t)(rg0 + ty + r) * SEQ + t0 + tx] = tile[tx][ty + r];
}

// ---------------- LayerNorm fp32 in -> bf16 out ------------------------------
__global__ __launch_bounds__(256) void ln_kernel(const float* __restrict__ xin,
                                                 const float* __restrict__ gamma,
                                                 const float* __restrict__ beta,
                                                 u16* __restrict__ out) {
  const int row = blockIdx.x, tid = threadIdx.x;
  const float4 v = reinterpret_cast<const float4*>(xin + (size_t)row * EMBED)[tid];
  float s  = v.x + v.y + v.z + v.w;
  float ss = v.x * v.x + v.y * v.y + v.z * v.z + v.w * v.w;
#pragma unroll
  for (int m = 1; m < 64; m <<= 1) { s += __shfl_xor(s, m); ss += __shfl_xor(ss, m); }
  __shared__ float red[8];
  if ((tid & 63) == 0) { red[tid >> 6] = s; red[4 + (tid >> 6)] = ss; }
  __syncthreads();
  s  = red[0] + red[1] + red[2] + red[3];
  ss = red[4] + red[5] + red[6] + red[7];
  const float mean = s * (1.0f / EMBED);
  const float var  = ss * (1.0f / EMBED) - mean * mean;
  const float rstd = rsqrtf(var + 1e-5f);
  const float4 g  = reinterpret_cast<const float4*>(gamma)[tid];
  const float4 bb = reinterpret_cast<const float4*>(beta)[tid];
  ushort4 o;
  o.x = f2bf((v.x - mean) * rstd * g.x + bb.x);
  o.y = f2bf((v.y - mean) * rstd * g.y + bb.y);
  o.z = f2bf((v.z - mean) * rstd * g.z + bb.z);
  o.w = f2bf((v.w - mean) * rstd * g.w + bb.w);
  reinterpret_cast<ushort4*>(out + (size_t)row * EMBED)[tid] = o;
}

// ---------------- bf16 GEMM v7: 2-phase/tile, dual-B regs, counted vmcnt -----
// 256xBN, 8 waves, per-wave 128x64 (NREP=4) / 128x32 (NREP=2).
// Per K-tile t (buf c), 2 phases:
//  ph1: rd A0,B0,B1 | stage B0',B1',A0' (cn) | bar lgkm0 | 32 MFMA (q00,q01) | bar
//  ph2: vm(VH) | rd A1 | stage A1' (cn)      | bar lgkm0 | 32 MFMA (q11,q10) | vm(2) bar
// In-flight invariant at tile entry: only A1(t) (2 loads) flying. Never drains.
// Stages go ONLY to the dead buffer cn -> race-free by construction.
// EPI 0: bf16 | 1: +bias +res -> fp32 | 2: +bias GELU -> bf16
template <int NREP, int EPI>
__global__ __launch_bounds__(512, 2) void gemm7(const u16* __restrict__ A,
                                                const u16* __restrict__ Bt,
                                                void* __restrict__ Cv,
                                                const float* __restrict__ bias,
                                                const float* __restrict__ res,
                                                int M, int N, int K) {
  constexpr int BN = NREP * 64;
  constexpr int VH = (NREP == 4) ? 6 : 4;          // ph2-head gate
  __shared__ __align__(16) u16 As[2][256 * 64];    // [row][k] swizzled
  __shared__ __align__(16) u16 Bs[2][BN * 64];     // [col][k] swizzled

  const int tid = threadIdx.x;
  const int lane = tid & 63, wid = tid >> 6;
  const int l4 = lane >> 4, l15 = lane & 15;
  const int wq = wid >> 2, wn = wid & 3;

  const int gx = gridDim.x;
  const int nwg = gx * (int)gridDim.y;
  const int flat = (int)blockIdx.y * gx + (int)blockIdx.x;
  const int cpx = nwg >> 3;                        // bijective XCD swizzle
  const int swz = (flat & 7) * cpx + (flat >> 3);
  const int brow = (swz / gx) << 8;
  const int bcol = (swz % gx) * BN;

  const f32x4 z4 = {0.f, 0.f, 0.f, 0.f};
  f32x4 acc[4][4][NREP / 2];                       // [quadrant][m][n2]
#pragma unroll
  for (int q = 0; q < 4; ++q)
#pragma unroll
    for (int m = 0; m < 4; ++m)
#pragma unroll
      for (int n = 0; n < NREP / 2; ++n) acc[q][m][n] = z4;

  const int srow = tid >> 3;                       // 0..63
  const int scolb = ((tid & 7) << 4) ^ ((srow & 7) << 4);
  const u16* gAs = A  + (size_t)(brow + srow) * K + (scolb >> 1);
  const u16* gBs = Bt + (size_t)(bcol + srow) * K + (scolb >> 1);
  const int lA = wid * 512;                        // wave-uniform LDS u16 base

  const int nk = K >> 6;

#define STAGE_A(c_, t_, h_)                                                     \
  do {                                                                          \
    gload16(gAs + (size_t)((h_) * 128) * K + (size_t)(t_) * 64,                 \
            &As[c_][(h_) * 8192 + lA]);                                         \
    gload16(gAs + (size_t)((h_) * 128 + 64) * K + (size_t)(t_) * 64,            \
            &As[c_][(h_) * 8192 + 4096 + lA]);                                  \
  } while (0)
#define STAGE_B(c_, t_, h_)                                                     \
  do {                                                                          \
    if constexpr (NREP == 4) {                                                  \
      gload16(gBs + (size_t)((h_) * 128) * K + (size_t)(t_) * 64,               \
              &Bs[c_][(h_) * 8192 + lA]);                                       \
      gload16(gBs + (size_t)((h_) * 128 + 64) * K + (size_t)(t_) * 64,          \
              &Bs[c_][(h_) * 8192 + 4096 + lA]);                                \
    } else {                                                                    \
      gload16(gBs + (size_t)((h_) * 64) * K + (size_t)(t_) * 64,                \
              &Bs[c_][(h_) * 4096 + lA]);                                       \
    }                                                                           \
  } while (0)

  const int kk0  = l4 << 3;
  const int aswz = (l15 & 7) << 3;

#define RD_A(MH)                                                                \
  _Pragma("unroll")                                                             \
  for (int m_ = 0; m_ < 4; ++m_)                                                \
    _Pragma("unroll")                                                           \
    for (int ks_ = 0; ks_ < 2; ++ks_)                                           \
      af[m_][ks_] = *(const bf16x8*)&As[c][((MH) * 128 + wq * 64 + m_ * 16 + l15) * 64 + ((kk0 + ks_ * 32) ^ aswz)];
#define RD_B(DST, NH)                                                           \
  _Pragma("unroll")                                                             \
  for (int n_ = 0; n_ < NREP / 2; ++n_)                                         \
    _Pragma("unroll")                                                           \
    for (int ks_ = 0; ks_ < 2; ++ks_)                                           \
      DST[n_][ks_] = *(const bf16x8*)&Bs[c][((NH) * (BN / 2) + wn * (BN / 8) + n_ * 16 + l15) * 64 + ((kk0 + ks_ * 32) ^ aswz)];
#define GATE_LG                                                                 \
  __builtin_amdgcn_s_barrier();                                                 \
  asm volatile("s_waitcnt lgkmcnt(0)" ::: "memory");                            \
  __builtin_amdgcn_sched_barrier(0)
#define VM(N_) asm volatile("s_waitcnt vmcnt(%0)" :: "i"(N_) : "memory")
#define MFMA_Q(Q_, BF_)                                                         \
  _Pragma("unroll")                                                             \
  for (int m_ = 0; m_ < 4; ++m_)                                                \
    _Pragma("unroll")                                                           \
    for (int n_ = 0; n_ < NREP / 2; ++n_)                                       \
      _Pragma("unroll")                                                         \
      for (int ks_ = 0; ks_ < 2; ++ks_)                                         \
        acc[Q_][m_][n_] = __builtin_amdgcn_mfma_f32_16x16x32_bf16(              \
            af[m_][ks_], BF_[n_][ks_], acc[Q_][m_][n_], 0, 0, 0);

  bf16x8 af[4][2], bf0[NREP / 2][2], bf1[NREP / 2][2];

  // prologue: stage tile0 as {A0,B0,B1} then A1; gate leaves A1(0) flying
  STAGE_A(0, 0, 0);
  STAGE_B(0, 0, 0);
  STAGE_B(0, 0, 1);
  STAGE_A(0, 0, 1);
  VM(2);
  __builtin_amdgcn_s_barrier();

  for (int t = 0; t < nk; ++t) {
    const int c = t & 1, cn = c ^ 1;
    // ---- ph1: quadrants (0,0),(0,1) ----
    RD_A(0); RD_B(bf0, 0); RD_B(bf1, 1);
    if (t + 1 < nk) { STAGE_B(cn, t + 1, 0); STAGE_B(cn, t + 1, 1); STAGE_A(cn, t + 1, 0); }
    GATE_LG;
    __builtin_amdgcn_s_setprio(1);
    MFMA_Q(0, bf0);
    MFMA_Q(1, bf1);
    __builtin_amdgcn_s_setprio(0);
    __builtin_amdgcn_s_barrier();
    // ---- ph2: quadrants (1,1),(1,0) ----
    if (t + 1 < nk) { VM(VH); } else { VM(0); }    // A1(t) landed
    RD_A(1);
    if (t + 1 < nk) STAGE_A(cn, t + 1, 1);
    GATE_LG;
    __builtin_amdgcn_s_setprio(1);
    MFMA_Q(2, bf1);
    MFMA_Q(3, bf0);
    __builtin_amdgcn_s_setprio(0);
    VM(2);                                         // t+1's {B0,B1,A0} landed
    __builtin_amdgcn_s_barrier();
  }

#undef STAGE_A
#undef STAGE_B
#undef RD_A
#undef RD_B
#undef GATE_LG
#undef VM
#undef MFMA_Q

  // epilogue: C/D layout col = lane&15, row = (lane>>4)*4 + reg
#pragma unroll
  for (int q = 0; q < 4; ++q) {
    const int mh = q >> 1, nh = (q >> 1) ^ (q & 1);
    const int rowb = brow + mh * 128 + wq * 64 + (l4 << 2);
    const int colb = bcol + nh * (BN / 2) + wn * (BN / 8) + l15;
#pragma unroll
    for (int n = 0; n < NREP / 2; ++n) {
      const int col = colb + n * 16;
      float bv = 0.f;
      if (EPI != 0) bv = bias[col];
#pragma unroll
      for (int m = 0; m < 4; ++m) {
#pragma unroll
        for (int j = 0; j < 4; ++j) {
          const int row = rowb + m * 16 + j;
          const float v = acc[q][m][n][j];
          if (EPI == 0) {
            ((u16*)Cv)[(size_t)row * N + col] = f2bf(v);
          } else if (EPI == 1) {
            ((float*)Cv)[(size_t)row * N + col] = v + bv + res[(size_t)row * N + col];
          } else {
            const float t2 = v + bv;
            const float gl = 0.5f * t2 * (1.0f + erff(t2 * 0.70710678118654752f));
            ((u16*)Cv)[(size_t)row * N + col] = f2bf(gl);
          }
        }
      }
    }
  }
}

// ---------------- causal flash attention v5b (unchanged) ---------------------
__global__ __launch_bounds__(512) void attn_fwd(const u16* __restrict__ qkv,
                                                const u16* __restrict__ Vt,
                                                u16* __restrict__ attn) {
  __shared__ __align__(16) u16 Ks[64 * 72];
  __shared__ __align__(16) u16 Vs[64 * 72];
  __shared__ __align__(16) u16 Ps[8 * 16 * 72];
  const int tid = threadIdx.x, lane = tid & 63, wid = tid >> 6;
  const int l4 = lane >> 4, l15 = lane & 15;
  const int bh = blockIdx.y, b = bh >> 4, h = bh & 15;
  const size_t bt0 = (size_t)b * SEQ;
  u16* Pw = &Ps[wid * 16 * 72];

  const int sr = tid >> 3;
  const int sc0 = (tid & 7) << 3;
  const u16* kbase = qkv + bt0 * 3072 + 1024 + h * 64;
  const u16* vbase = Vt + (size_t)bh * 64 * SEQ;
  const f32x4 z4 = {0.f, 0.f, 0.f, 0.f};

#pragma unroll
  for (int ph = 0; ph < 2; ++ph) {
    const int Qb = ((ph == 0) ? (int)blockIdx.x : 15 - (int)blockIdx.x) << 7;
    const int qw = Qb + wid * 16;
    const int qlane = qw + l15;

    const u16* qp = qkv + (bt0 + qlane) * 3072 + h * 64 + (l4 << 3);
    const bf16x8 aq0 = *(const bf16x8*)qp;
    const bf16x8 aq1 = *(const bf16x8*)(qp + 32);

    f32x4 o[4];
#pragma unroll
    for (int dt = 0; dt < 4; ++dt) o[dt] = z4;
    float mrun = -1e30f, lrun = 0.f;

    bf16x8 kp = *(const bf16x8*)(kbase + (size_t)sr * 3072 + sc0);
    bf16x8 vp = *(const bf16x8*)(vbase + (size_t)sr * SEQ + sc0);

    const int jend = Qb + 128;
    for (int j0 = 0; j0 < jend; j0 += 64) {
      __syncthreads();
      *(bf16x8*)&Ks[sr * 72 + sc0] = kp;
      *(bf16x8*)&Vs[sr * 72 + sc0] = vp;
      __syncthreads();

      if (j0 + 64 < jend) {
        kp = *(const bf16x8*)(kbase + (size_t)(j0 + 64 + sr) * 3072 + sc0);
        vp = *(const bf16x8*)(vbase + (size_t)sr * SEQ + j0 + 64 + sc0);
      }

      if (j0 > qw + 15) continue;
      const int nt = min(4, ((qw + 15 - j0) >> 4) + 1);

      f32x4 s[4];
#pragma unroll
      for (int t = 0; t < 4; ++t) {
        if (t < nt) {
          const bf16x8 ak0 = *(const bf16x8*)&Ks[(t * 16 + l15) * 72 + (l4 << 3)];
          const bf16x8 ak1 = *(const bf16x8*)&Ks[(t * 16 + l15) * 72 + 32 + (l4 << 3)];
          f32x4 a = z4;
          a = __builtin_amdgcn_mfma_f32_16x16x32_bf16(ak0, aq0, a, 0, 0, 0);
          a = __builtin_amdgcn_mfma_f32_16x16x32_bf16(ak1, aq1, a, 0, 0, 0);
          s[t] = a;
        }
      }

      float mt = -1e30f;
#pragma unroll
      for (int t = 0; t < 4; ++t) {
        if (t < nt) {
          if (j0 + t * 16 + 15 > qw) {
            const int kvb = j0 + t * 16 + (l4 << 2);
#pragma unroll
            for (int j = 0; j < 4; ++j)
              if (kvb + j > qlane) s[t][j] = -1e30f;
          }
          mt = fmaxf(mt, fmaxf(fmaxf(s[t][0], s[t][1]), fmaxf(s[t][2], s[t][3])));
        }
      }
      mt = fmaxf(mt, __shfl_xor(mt, 16));
      mt = fmaxf(mt, __shfl_xor(mt, 32));

      const bool skip = __all(mt <= mrun + 44.0f);
      float scq = 1.0f;
      if (!skip) {
        const float mn = fmaxf(mrun, mt);
        scq = exp2f((mrun - mn) * ATT_C);
        mrun = mn;
      }
      const float mc = mrun * ATT_C;

      float ls = 0.f;
      uint2 pw[4];
#pragma unroll
      for (int t = 0; t < 4; ++t) {
        if (t < nt) {
          const float p0 = exp2f(__builtin_fmaf(s[t][0], ATT_C, -mc));
          const float p1 = exp2f(__builtin_fmaf(s[t][1], ATT_C, -mc));
          const float p2 = exp2f(__builtin_fmaf(s[t][2], ATT_C, -mc));
          const float p3 = exp2f(__builtin_fmaf(s[t][3], ATT_C, -mc));
          ls += (p0 + p1) + (p2 + p3);
          pw[t].x = cvtpk(p0, p1);
          pw[t].y = cvtpk(p2, p3);
        } else {
          pw[t].x = 0u; pw[t].y = 0u;
        }
      }
#pragma unroll
      for (int t = 0; t < 4; ++t)
        *(uint2*)&Pw[l15 * 72 + t * 16 + (l4 << 2)] = pw[t];

      ls += __shfl_xor(ls, 16);
      ls += __shfl_xor(ls, 32);

      if (!skip) {
        lrun = lrun * scq + ls;
#pragma unroll
        for (int dt = 0; dt < 4; ++dt)
#pragma unroll
          for (int j = 0; j < 4; ++j) o[dt][j] *= scq;
      } else {
        lrun += ls;
      }

      const int nc = (nt + 1) >> 1;
#pragma unroll
      for (int c = 0; c < 2; ++c) {
        if (c < nc) {
          const bf16x8 ap = *(const bf16x8*)&Pw[l15 * 72 + c * 32 + (l4 << 3)];
#pragma unroll
          for (int dt = 0; dt < 4; ++dt) {
            const bf16x8 bv = *(const bf16x8*)&Vs[(dt * 16 + l15) * 72 + c * 32 + (l4 << 3)];
            o[dt] = __builtin_amdgcn_mfma_f32_16x16x32_bf16(bv, ap, o[dt], 0, 0, 0);
          }
        }
      }
    }

    const float rl = 1.0f / lrun;
#pragma unroll
    for (int dt = 0; dt < 4; ++dt) {
      uint2 w;
      w.x = cvtpk(o[dt][0] * rl, o[dt][1] * rl);
      w.y = cvtpk(o[dt][2] * rl, o[dt][3] * rl);
      *(uint2*)&Pw[l15 * 72 + dt * 16 + (l4 << 2)] = w;
    }
#pragma unroll
    for (int rep = 0; rep < 2; ++rep) {
      const int unit = rep * 64 + lane;
      const int r = unit >> 3, c = unit & 7;
      const bf16x8 v = *(const bf16x8*)&Pw[r * 72 + c * 8];
      *(bf16x8*)&attn[(bt0 + qw + r) * EMBED + h * 64 + c * 8] = v;
    }
  }
}

// ---------------- driver ------------------------------------------------------
extern "C" void kernel_launch(void* const* d_in, const int* in_sizes, int n_in,
                              void* d_out, int out_size, void* d_ws, size_t ws_size,
                              hipStream_t stream) {
  const float* x   = (const float*)d_in[0];
  const float* Wq  = (const float*)d_in[1];
  const float* Wk  = (const float*)d_in[2];
  const float* Wv  = (const float*)d_in[3];
  const float* Wo  = (const float*)d_in[4];
  const float* bo  = (const float*)d_in[5];
  const float* W1  = (const float*)d_in[6];
  const float* b1  = (const float*)d_in[7];
  const float* W2  = (const float*)d_in[8];
  const float* b2  = (const float*)d_in[9];
  const float* g1  = (const float*)d_in[10];
  const float* be1 = (const float*)d_in[11];
  const float* g2  = (const float*)d_in[12];
  const float* be2 = (const float*)d_in[13];

  char* ws = (char*)d_ws;
  u16* wqkv_t = (u16*)(ws + 0);                 // [3072][1024] bf16   6 MB
  u16* wo_t   = (u16*)(ws + 6291456);           // [1024][1024]        2 MB
  u16* w1_t   = (u16*)(ws + 8388608);           // [4096][1024]        8 MB
  u16* w2_t   = (u16*)(ws + 16777216);          // [1024][4096]        8 MB
  u16* hbuf   = (u16*)(ws + 25165824);          // LN out, reused     16 MB
  u16* qkv    = (u16*)(ws + 41943040);          // [8192][3072]       48 MB
  u16* ff1    = (u16*)(ws + 41943040);          // overlaps qkv+Vt    64 MB
  u16* vt     = (u16*)(ws + 92274688);          // [64*64][2048]      16 MB
  u16* attnb  = (u16*)(ws + 109051904);         // [8192][1024]       16 MB
  float* x2   = (float*)(ws + 125829120);       // fp32 residual      32 MB
  float* outp = (float*)d_out;

  dim3 blk(256);
  wtrans<<<dim3(32, 32),  blk, 0, stream>>>(Wq, wqkv_t,               1024, 1024);
  wtrans<<<dim3(32, 32),  blk, 0, stream>>>(Wk, wqkv_t + 1024 * 1024, 1024, 1024);
  wtrans<<<dim3(32, 32),  blk, 0, stream>>>(Wv, wqkv_t + 2048 * 1024, 1024, 1024);
  wtrans<<<dim3(32, 32),  blk, 0, stream>>>(Wo, wo_t,                 1024, 1024);
  wtrans<<<dim3(128, 32), blk, 0, stream>>>(W1, w1_t,                 1024, 4096);
  wtrans<<<dim3(32, 128), blk, 0, stream>>>(W2, w2_t,                 4096, 1024);

  ln_kernel<<<dim3(8192), blk, 0, stream>>>(x, g1, be1, hbuf);
  gemm7<2, 0><<<dim3(24, 32), dim3(512), 0, stream>>>(hbuf, wqkv_t, qkv, nullptr, nullptr,
                                                      8192, 3072, 1024);
  vtrans<<<dim3(64, 128), blk, 0, stream>>>(qkv, vt);
  attn_fwd<<<dim3(8, 64), dim3(512), 0, stream>>>(qkv, vt, attnb);
  gemm7<2, 1><<<dim3(8, 32), dim3(512), 0, stream>>>(attnb, wo_t, x2, bo, x,
                                                     8192, 1024, 1024);
  ln_kernel<<<dim3(8192), blk, 0, stream>>>(x2, g2, be2, hbuf);
  gemm7<4, 2><<<dim3(16, 32), dim3(512), 0, stream>>>(hbuf, w1_t, ff1, b1, nullptr,
                                                      8192, 4096, 1024);
  gemm7<2, 1><<<dim3(8, 32), dim3(512), 0, stream>>>(ff1, w2_t, outp, b2, x2,
                                                     8192, 1024, 4096);
}